// Round 1
// baseline (292.434 us; speedup 1.0000x reference)
//
#include <hip/hip_runtime.h>
#include <hip/hip_bf16.h>
#include <stdint.h>

// Problem constants (fixed shape): B=16, L=65536, H=64, K=64
#define LCOUNT 65536
#define LOUT   65473   // L - (H-1)
#define KF     64
#define HH     64
#define TL     256     // output positions per block

typedef __attribute__((ext_vector_type(8))) short  short8;   // 8 bf16 (4 VGPRs)
typedef __attribute__((ext_vector_type(4))) float  float4v;  // 4 fp32

__device__ __forceinline__ unsigned short f2bf(float f) {
    union { float f; uint32_t u; } c; c.f = f;
    uint32_t u = c.u;
    u += 0x7FFFu + ((u >> 16) & 1u);   // round-to-nearest-even
    return (unsigned short)(u >> 16);
}

__global__ __launch_bounds__(256)
void hankel_kernel(const float* __restrict__ x,
                   const float* __restrict__ W,
                   const float* __restrict__ bias,
                   float* __restrict__ out)
{
    __shared__ float          xs_f[TL + 64];
    __shared__ unsigned short xs_b[TL + 64];
    __shared__ float          mu_s[TL];
    __shared__ float          inv_s[TL];
    __shared__ float          wsum_s[KF];

    const int tid  = threadIdx.x;
    const int lane = tid & 63;
    const int wv   = tid >> 6;
    const int m    = lane & 15;   // col within 16-wide n-tile / A-row
    const int quad = lane >> 4;

    const int tile     = blockIdx.x;
    const int bb       = blockIdx.y;
    const int block_lo = tile * TL;

    // ---- stage x tile: fp32 (for stats) + bf16 (for MFMA A) ----
    const float* xrow = x + (size_t)bb * LCOUNT;
    for (int i = tid; i < TL + 64; i += 256) {
        int gi = block_lo + i;
        if (gi > LCOUNT - 1) gi = LCOUNT - 1;   // tail clamp; masked at store
        float v = xrow[gi];
        xs_f[i] = v;
        xs_b[i] = f2bf(v);
    }

    // ---- Wsum[k] = sum_h W[k,h] (threads 0..63) ----
    if (tid < KF) {
        float s = 0.f;
        const float* wr = W + tid * HH;
        #pragma unroll
        for (int h = 0; h < HH; ++h) s += wr[h];
        wsum_s[tid] = s;
    }

    // ---- B fragments in registers: B[h][n], n = t*16 + m, h = quad*8 + j + ki*32 ----
    short8 bfrag[4][2];
    float  biasr[4];
    #pragma unroll
    for (int t = 0; t < 4; ++t) {
        const int k = t * 16 + m;               // filter index (n)
        biasr[t] = bias[k];
        #pragma unroll
        for (int ki = 0; ki < 2; ++ki) {
            const float4v* wp = (const float4v*)(W + k * HH + quad * 8 + ki * 32);
            float4v w0 = wp[0];
            float4v w1 = wp[1];
            short8 f;
            f[0] = (short)f2bf(w0[0]); f[1] = (short)f2bf(w0[1]);
            f[2] = (short)f2bf(w0[2]); f[3] = (short)f2bf(w0[3]);
            f[4] = (short)f2bf(w1[0]); f[5] = (short)f2bf(w1[1]);
            f[6] = (short)f2bf(w1[2]); f[7] = (short)f2bf(w1[3]);
            bfrag[t][ki] = f;
        }
    }

    __syncthreads();

    // ---- per-position window stats (one position per thread) ----
    {
        const int p = tid;
        float s1 = 0.f, s2 = 0.f;
        #pragma unroll 8
        for (int j = 0; j < HH; ++j) {
            float v = xs_f[p + j];
            s1 += v;
            s2 += v * v;
        }
        float mu  = s1 * (1.f / 64.f);
        float var = (s2 - 64.f * mu * mu) * (1.f / 63.f);
        var = var < 0.f ? 0.f : var;
        float sd  = sqrtf(var);
        mu_s[p]  = mu;
        inv_s[p] = 1.f / (sd + 1e-6f);
    }
    __syncthreads();

    float wsumr[4];
    #pragma unroll
    for (int t = 0; t < 4; ++t) wsumr[t] = wsum_s[t * 16 + m];

    // ---- MFMA phase: each wave handles groups of 16 positions ----
    for (int g = wv; g < TL / 16; g += 4) {
        const int p0    = g * 16;
        const int abase = p0 + m + quad * 8;   // A[m][h=quad*8+j(+32ki)] = xs[p0+m + h]

        short8 a0, a1;
        #pragma unroll
        for (int j = 0; j < 8; ++j) {
            a0[j] = (short)xs_b[abase + j];
            a1[j] = (short)xs_b[abase + 32 + j];
        }

        float4v acc[4];
        #pragma unroll
        for (int t = 0; t < 4; ++t) acc[t] = (float4v){0.f, 0.f, 0.f, 0.f};

        #pragma unroll
        for (int t = 0; t < 4; ++t) {
            acc[t] = __builtin_amdgcn_mfma_f32_16x16x32_bf16(a0, bfrag[t][0], acc[t], 0, 0, 0);
            acc[t] = __builtin_amdgcn_mfma_f32_16x16x32_bf16(a1, bfrag[t][1], acc[t], 0, 0, 0);
        }

        // ---- epilogue: fold layernorm + bias + relu, store ----
        const int prow = p0 + quad * 4;        // C/D row = quad*4 + reg
        float mur[4], invr[4];
        #pragma unroll
        for (int r = 0; r < 4; ++r) {
            mur[r]  = mu_s[prow + r];
            invr[r] = inv_s[prow + r];
        }
        #pragma unroll
        for (int r = 0; r < 4; ++r) {
            const int lo = block_lo + prow + r;
            if (lo < LOUT) {
                float* op = out + ((size_t)bb * LOUT + lo) * KF + m;
                #pragma unroll
                for (int t = 0; t < 4; ++t) {
                    float vv = (acc[t][r] - mur[r] * wsumr[t]) * invr[r] + biasr[t];
                    vv = vv > 0.f ? vv : 0.f;
                    op[t * 16] = vv;
                }
            }
        }
    }

    // ---- output 1: warmup scalar = 63 ----
    if (tile == 0 && bb == 0 && tid == 0) {
        out[(size_t)16 * LOUT * KF] = 63.0f;
    }
}

extern "C" void kernel_launch(void* const* d_in, const int* in_sizes, int n_in,
                              void* d_out, int out_size, void* d_ws, size_t ws_size,
                              hipStream_t stream) {
    const float* x = (const float*)d_in[0];   // (16, 65536) fp32
    const float* W = (const float*)d_in[1];   // (64, 64) fp32
    const float* b = (const float*)d_in[2];   // (64,) fp32
    float* out = (float*)d_out;               // 16*65473*64 fp32 + 1 (warmup)

    dim3 grid((LOUT + TL - 1) / TL, 16);      // 256 tiles x 16 batches
    hankel_kernel<<<grid, 256, 0, stream>>>(x, W, b, out);
}